// Round 1
// baseline (2990.826 us; speedup 1.0000x reference)
//
#include <hip/hip_runtime.h>

#define N_NODES 100000
#define N_EDGES 1600000
#define D 128

constexpr float LN_EPS   = 1e-5f;
constexpr float MEAN_EPS = 1e-8f;

// ---------------------------------------------------------------------------
// Phase 1: scatter  neighbor_sum[row] += x[col];  count[row] += 1
// 32 threads per edge, float4 per thread (128 floats/edge).
// ---------------------------------------------------------------------------
__global__ __launch_bounds__(256) void scatter_kernel(
    const float* __restrict__ x, const int* __restrict__ ei,
    float* __restrict__ nsum, float* __restrict__ ncnt) {
  int tid = blockIdx.x * 256 + threadIdx.x;
  int e = tid >> 5;        // edge index
  int c = tid & 31;        // float4 chunk within the 128-float row
  if (e >= N_EDGES) return;
  int row = ei[e];              // segment destination
  int col = ei[N_EDGES + e];    // gathered source row
  float4 v = ((const float4*)x)[col * 32 + c];
  float* dst = nsum + (size_t)row * D + c * 4;
  atomicAdd(dst + 0, v.x);
  atomicAdd(dst + 1, v.y);
  atomicAdd(dst + 2, v.z);
  atomicAdd(dst + 3, v.w);
  if (c == 0) atomicAdd(ncnt + row, 1.0f);
}

// ---------------------------------------------------------------------------
// Phase 2: fused GEMM (K=256: [x | mean] @ [W_self | W_agg]^T) + bias + relu
//          + LayerNorm.  Tile: 64 nodes x 128 outs, K-tile 64, 256 threads,
//          4x8 register tile per thread.
// ---------------------------------------------------------------------------
__global__ __launch_bounds__(256) void fused_gemm_ln(
    const float* __restrict__ x, const float* __restrict__ nsum,
    const float* __restrict__ ncnt,
    const float* __restrict__ Wself, const float* __restrict__ Wagg,
    const float* __restrict__ bself, const float* __restrict__ bagg,
    const float* __restrict__ gamma, const float* __restrict__ beta,
    float* __restrict__ out) {
  __shared__ float As[64 * 68];    // [node][k], +4 pad
  __shared__ float Bs[128 * 68];   // [out][k],  +4 pad

  const int t = threadIdx.x;
  const int tx = t & 15;           // output group: o = tx + 16*j
  const int ty = t >> 4;           // node group:   m = ty + 16*i
  const int base = blockIdx.x * 64;

  float acc[4][8];
#pragma unroll
  for (int i = 0; i < 4; ++i)
#pragma unroll
    for (int j = 0; j < 8; ++j) acc[i][j] = 0.0f;

  for (int kt = 0; kt < 4; ++kt) {
    const float* W = (kt < 2) ? Wself : Wagg;
    const int koff = (kt & 1) * 64;

    // stage B tile: 128x64 floats, 8 float4 per thread, coalesced
#pragma unroll
    for (int r = 0; r < 8; ++r) {
      int flat = r * 1024 + t * 4;
      int o = flat >> 6, kk = flat & 63;
      float4 w = *(const float4*)&W[o * 128 + koff + kk];
      *(float4*)&Bs[o * 68 + kk] = w;
    }
    // stage A tile: 64x64 floats, 4 float4 per thread
#pragma unroll
    for (int r = 0; r < 4; ++r) {
      int flat = r * 1024 + t * 4;
      int m = flat >> 6, kk = flat & 63;
      int node = base + m;
      float4 a = make_float4(0.f, 0.f, 0.f, 0.f);
      if (node < N_NODES) {
        if (kt < 2) {
          a = *(const float4*)&x[node * 128 + koff + kk];
        } else {
          float inv = 1.0f / (ncnt[node] + MEAN_EPS);
          float4 s = *(const float4*)&nsum[(size_t)node * 128 + koff + kk];
          a = make_float4(s.x * inv, s.y * inv, s.z * inv, s.w * inv);
        }
      }
      *(float4*)&As[m * 68 + kk] = a;
    }
    __syncthreads();

#pragma unroll
    for (int kc = 0; kc < 64; kc += 4) {
      float4 av[4], bv[8];
#pragma unroll
      for (int i = 0; i < 4; ++i)
        av[i] = *(const float4*)&As[(ty + 16 * i) * 68 + kc];
#pragma unroll
      for (int j = 0; j < 8; ++j)
        bv[j] = *(const float4*)&Bs[(tx + 16 * j) * 68 + kc];
#pragma unroll
      for (int i = 0; i < 4; ++i)
#pragma unroll
        for (int j = 0; j < 8; ++j) {
          acc[i][j] += av[i].x * bv[j].x;
          acc[i][j] += av[i].y * bv[j].y;
          acc[i][j] += av[i].z * bv[j].z;
          acc[i][j] += av[i].w * bv[j].w;
        }
    }
    __syncthreads();
  }

  // epilogue: bias + relu + LayerNorm (row = 16 consecutive lanes)
  float bias[8], g[8], bt[8];
#pragma unroll
  for (int j = 0; j < 8; ++j) {
    int o = tx + 16 * j;
    bias[j] = bself[o] + bagg[o];
    g[j] = gamma[o];
    bt[j] = beta[o];
  }
#pragma unroll
  for (int i = 0; i < 4; ++i) {
    int node = base + ty + 16 * i;
    if (node >= N_NODES) continue;
    float hv[8], s1 = 0.f, s2 = 0.f;
#pragma unroll
    for (int j = 0; j < 8; ++j) {
      float h = acc[i][j] + bias[j];
      h = fmaxf(h, 0.0f);
      hv[j] = h;
      s1 += h;
      s2 += h * h;
    }
#pragma unroll
    for (int m = 1; m < 16; m <<= 1) {
      s1 += __shfl_xor(s1, m, 64);
      s2 += __shfl_xor(s2, m, 64);
    }
    float mean = s1 * (1.0f / 128.0f);
    float var = s2 * (1.0f / 128.0f) - mean * mean;
    float rstd = rsqrtf(var + LN_EPS);
#pragma unroll
    for (int j = 0; j < 8; ++j) {
      int o = tx + 16 * j;
      out[(size_t)node * 128 + o] = (hv[j] - mean) * rstd * g[j] + bt[j];
    }
  }
}

extern "C" void kernel_launch(void* const* d_in, const int* in_sizes, int n_in,
                              void* d_out, int out_size, void* d_ws, size_t ws_size,
                              hipStream_t stream) {
  const float* x     = (const float*)d_in[0];
  const int*   ei    = (const int*)d_in[1];
  const float* Wagg  = (const float*)d_in[2];
  const float* bagg  = (const float*)d_in[3];
  const float* Wself = (const float*)d_in[4];
  const float* bself = (const float*)d_in[5];
  const float* gamma = (const float*)d_in[6];
  const float* beta  = (const float*)d_in[7];
  float* out = (float*)d_out;

  float* nsum = (float*)d_ws;                       // [N_NODES, 128]
  float* ncnt = nsum + (size_t)N_NODES * D;         // [N_NODES]

  hipMemsetAsync(d_ws, 0, ((size_t)N_NODES * D + N_NODES) * sizeof(float),
                 stream);

  int scatter_blocks = (N_EDGES * 32) / 256;        // 200000
  scatter_kernel<<<scatter_blocks, 256, 0, stream>>>(x, ei, nsum, ncnt);

  int gemm_blocks = (N_NODES + 63) / 64;            // 1563
  fused_gemm_ln<<<gemm_blocks, 256, 0, stream>>>(
      x, nsum, ncnt, Wself, Wagg, bself, bagg, gamma, beta, out);
}

// Round 2
// 554.437 us; speedup vs baseline: 5.3943x; 5.3943x over previous
//
#include <hip/hip_runtime.h>

#define N_NODES 100000
#define N_EDGES 1600000
#define D 128
#define NB 391   // ceil(N_NODES / 256)

constexpr float LN_EPS   = 1e-5f;
constexpr float MEAN_EPS = 1e-8f;

// ---------------------------------------------------------------------------
// CSR build, step 1: histogram of destination rows
// ---------------------------------------------------------------------------
__global__ __launch_bounds__(256) void hist_kernel(const int* __restrict__ ei,
                                                   int* __restrict__ counts) {
  int e = blockIdx.x * 256 + threadIdx.x;
  if (e < N_EDGES) atomicAdd(&counts[ei[e]], 1);
}

// step 2a: per-256-chunk partial sums
__global__ __launch_bounds__(256) void scan_partials(const int* __restrict__ counts,
                                                     int* __restrict__ partials) {
  __shared__ int s[256];
  int i = blockIdx.x * 256 + threadIdx.x;
  s[threadIdx.x] = (i < N_NODES) ? counts[i] : 0;
  __syncthreads();
  for (int off = 128; off > 0; off >>= 1) {
    if (threadIdx.x < off) s[threadIdx.x] += s[threadIdx.x + off];
    __syncthreads();
  }
  if (threadIdx.x == 0) partials[blockIdx.x] = s[0];
}

// step 2b: single-block exclusive scan of NB partials (in place)
__global__ __launch_bounds__(256) void scan_block(int* __restrict__ partials) {
  __shared__ int s[256];
  __shared__ int carry;
  if (threadIdx.x == 0) carry = 0;
  __syncthreads();
  for (int base = 0; base < NB; base += 256) {
    int i = base + threadIdx.x;
    int v = (i < NB) ? partials[i] : 0;
    s[threadIdx.x] = v;
    __syncthreads();
    for (int off = 1; off < 256; off <<= 1) {
      int t = (threadIdx.x >= off) ? s[threadIdx.x - off] : 0;
      __syncthreads();
      s[threadIdx.x] += t;
      __syncthreads();
    }
    int excl = s[threadIdx.x] - v + carry;
    if (i < NB) partials[i] = excl;
    __syncthreads();          // everyone has read carry & s
    if (threadIdx.x == 0) carry += s[255];
    __syncthreads();
  }
}

// step 2c: per-chunk local scan + chunk base -> offsets, cursor
__global__ __launch_bounds__(256) void scan_final(const int* __restrict__ counts,
                                                  const int* __restrict__ partials,
                                                  int* __restrict__ offsets,
                                                  int* __restrict__ cursor) {
  __shared__ int s[256];
  int i = blockIdx.x * 256 + threadIdx.x;
  int v = (i < N_NODES) ? counts[i] : 0;
  s[threadIdx.x] = v;
  __syncthreads();
  for (int off = 1; off < 256; off <<= 1) {
    int t = (threadIdx.x >= off) ? s[threadIdx.x - off] : 0;
    __syncthreads();
    s[threadIdx.x] += t;
    __syncthreads();
  }
  int excl = s[threadIdx.x] - v + partials[blockIdx.x];
  if (i < N_NODES) {
    offsets[i] = excl;
    cursor[i]  = excl;
  }
  if (i == N_NODES - 1) offsets[N_NODES] = N_EDGES;
}

// step 3: scatter col indices into CSR order
__global__ __launch_bounds__(256) void scatter_csr(const int* __restrict__ ei,
                                                   int* __restrict__ cursor,
                                                   int* __restrict__ csr_col) {
  int e = blockIdx.x * 256 + threadIdx.x;
  if (e >= N_EDGES) return;
  int row = ei[e];
  int col = ei[N_EDGES + e];
  int pos = atomicAdd(&cursor[row], 1);
  csr_col[pos] = col;
}

// ---------------------------------------------------------------------------
// Phase 2: pull-mode mean aggregation. One wave per node; 64 lanes x float2
// cover the 128-float row; edges iterated wave-uniformly (no divergence, no
// atomics). Writes the MEAN directly into mean_out (aliases d_out).
// ---------------------------------------------------------------------------
__global__ __launch_bounds__(256) void aggregate_mean(
    const float* __restrict__ x, const int* __restrict__ offsets,
    const int* __restrict__ csr_col, float* mean_out) {
  int wave = (blockIdx.x * 256 + threadIdx.x) >> 6;
  int lane = threadIdx.x & 63;
  if (wave >= N_NODES) return;
  int beg = offsets[wave];
  int deg = offsets[wave + 1] - beg;
  float2 acc = make_float2(0.f, 0.f);
  for (int j0 = 0; j0 < deg; j0 += 64) {
    int cnt = deg - j0; if (cnt > 64) cnt = 64;
    int c = (j0 + lane < deg) ? csr_col[beg + j0 + lane] : 0;
    for (int e = 0; e < cnt; ++e) {
      int col = __shfl(c, e, 64);
      float2 v = ((const float2*)x)[col * 64 + lane];
      acc.x += v.x;
      acc.y += v.y;
    }
  }
  float inv = 1.0f / ((float)deg + MEAN_EPS);
  ((float2*)mean_out)[(size_t)wave * 64 + lane] = make_float2(acc.x * inv, acc.y * inv);
}

// ---------------------------------------------------------------------------
// Phase 3: fused GEMM (K=256: [x | mean] @ [W_self | W_agg]^T) + bias + relu
//          + LayerNorm. mean buffer aliases out: each block reads mean rows
//          only for its own node range, then overwrites them (reads complete
//          before epilogue stores within the block; no cross-block overlap).
// ---------------------------------------------------------------------------
__global__ __launch_bounds__(256) void fused_gemm_ln(
    const float* __restrict__ x, const float* mean_in,
    const float* __restrict__ Wself, const float* __restrict__ Wagg,
    const float* __restrict__ bself, const float* __restrict__ bagg,
    const float* __restrict__ gamma, const float* __restrict__ beta,
    float* out) {
  __shared__ float As[64 * 68];    // [node][k], +4 pad
  __shared__ float Bs[128 * 68];   // [out][k],  +4 pad

  const int t = threadIdx.x;
  const int tx = t & 15;           // output group: o = tx + 16*j
  const int ty = t >> 4;           // node group:   m = ty + 16*i
  const int base = blockIdx.x * 64;

  float acc[4][8];
#pragma unroll
  for (int i = 0; i < 4; ++i)
#pragma unroll
    for (int j = 0; j < 8; ++j) acc[i][j] = 0.0f;

  for (int kt = 0; kt < 4; ++kt) {
    const float* W = (kt < 2) ? Wself : Wagg;
    const float* A = (kt < 2) ? x : mean_in;
    const int koff = (kt & 1) * 64;

    // stage B tile: 128x64 floats, 8 float4 per thread, coalesced
#pragma unroll
    for (int r = 0; r < 8; ++r) {
      int flat = r * 1024 + t * 4;
      int o = flat >> 6, kk = flat & 63;
      float4 w = *(const float4*)&W[o * 128 + koff + kk];
      *(float4*)&Bs[o * 68 + kk] = w;
    }
    // stage A tile: 64x64 floats, 4 float4 per thread
#pragma unroll
    for (int r = 0; r < 4; ++r) {
      int flat = r * 1024 + t * 4;
      int m = flat >> 6, kk = flat & 63;
      int node = base + m;
      float4 a = make_float4(0.f, 0.f, 0.f, 0.f);
      if (node < N_NODES) a = *(const float4*)&A[(size_t)node * 128 + koff + kk];
      *(float4*)&As[m * 68 + kk] = a;
    }
    __syncthreads();

#pragma unroll
    for (int kc = 0; kc < 64; kc += 4) {
      float4 av[4], bv[8];
#pragma unroll
      for (int i = 0; i < 4; ++i)
        av[i] = *(const float4*)&As[(ty + 16 * i) * 68 + kc];
#pragma unroll
      for (int j = 0; j < 8; ++j)
        bv[j] = *(const float4*)&Bs[(tx + 16 * j) * 68 + kc];
#pragma unroll
      for (int i = 0; i < 4; ++i)
#pragma unroll
        for (int j = 0; j < 8; ++j) {
          acc[i][j] += av[i].x * bv[j].x;
          acc[i][j] += av[i].y * bv[j].y;
          acc[i][j] += av[i].z * bv[j].z;
          acc[i][j] += av[i].w * bv[j].w;
        }
    }
    __syncthreads();
  }

  // epilogue: bias + relu + LayerNorm (row = 16 consecutive lanes)
  float bias[8], g[8], bt[8];
#pragma unroll
  for (int j = 0; j < 8; ++j) {
    int o = tx + 16 * j;
    bias[j] = bself[o] + bagg[o];
    g[j] = gamma[o];
    bt[j] = beta[o];
  }
#pragma unroll
  for (int i = 0; i < 4; ++i) {
    int node = base + ty + 16 * i;
    if (node >= N_NODES) continue;
    float hv[8], s1 = 0.f, s2 = 0.f;
#pragma unroll
    for (int j = 0; j < 8; ++j) {
      float h = acc[i][j] + bias[j];
      h = fmaxf(h, 0.0f);
      hv[j] = h;
      s1 += h;
      s2 += h * h;
    }
#pragma unroll
    for (int m = 1; m < 16; m <<= 1) {
      s1 += __shfl_xor(s1, m, 64);
      s2 += __shfl_xor(s2, m, 64);
    }
    float mean = s1 * (1.0f / 128.0f);
    float var = s2 * (1.0f / 128.0f) - mean * mean;
    float rstd = rsqrtf(var + LN_EPS);
#pragma unroll
    for (int j = 0; j < 8; ++j) {
      int o = tx + 16 * j;
      out[(size_t)node * 128 + o] = (hv[j] - mean) * rstd * g[j] + bt[j];
    }
  }
}

extern "C" void kernel_launch(void* const* d_in, const int* in_sizes, int n_in,
                              void* d_out, int out_size, void* d_ws, size_t ws_size,
                              hipStream_t stream) {
  const float* x     = (const float*)d_in[0];
  const int*   ei    = (const int*)d_in[1];
  const float* Wagg  = (const float*)d_in[2];
  const float* bagg  = (const float*)d_in[3];
  const float* Wself = (const float*)d_in[4];
  const float* bself = (const float*)d_in[5];
  const float* gamma = (const float*)d_in[6];
  const float* beta  = (const float*)d_in[7];
  float* out = (float*)d_out;

  // workspace layout (ints): counts | partials | offsets | cursor | csr_col
  int* counts   = (int*)d_ws;                  // N_NODES
  int* partials = counts + N_NODES;            // NB (rounded up)
  int* offsets  = partials + 512;              // N_NODES + 1
  int* cursor   = offsets + N_NODES + 1;       // N_NODES
  int* csr_col  = cursor + N_NODES;            // N_EDGES   (~7.6 MB total)

  hipMemsetAsync(counts, 0, N_NODES * sizeof(int), stream);

  int eb = (N_EDGES + 255) / 256;
  hist_kernel<<<eb, 256, 0, stream>>>(ei, counts);
  scan_partials<<<NB, 256, 0, stream>>>(counts, partials);
  scan_block<<<1, 256, 0, stream>>>(partials);
  scan_final<<<NB, 256, 0, stream>>>(counts, partials, offsets, cursor);
  scatter_csr<<<eb, 256, 0, stream>>>(ei, cursor, csr_col);

  // mean aggregation writes into d_out (reused as scratch; GEMM consumes it
  // per-block before overwriting the same rows)
  int ab = (N_NODES * 64 + 255) / 256;   // one wave per node, 4 waves/block
  aggregate_mean<<<ab, 256, 0, stream>>>(x, offsets, csr_col, out);

  int gb = (N_NODES + 63) / 64;
  fused_gemm_ln<<<gb, 256, 0, stream>>>(
      x, out, Wself, Wagg, bself, bagg, gamma, beta, out);
}

// Round 3
// 464.592 us; speedup vs baseline: 6.4375x; 1.1934x over previous
//
#include <hip/hip_runtime.h>

#define N_NODES 100000
#define N_EDGES 1600000
#define D 128
#define NB 391   // ceil(N_NODES / 256)

constexpr float LN_EPS   = 1e-5f;
constexpr float MEAN_EPS = 1e-8f;

typedef __attribute__((ext_vector_type(8))) short bf16x8;
typedef __attribute__((ext_vector_type(4))) float f32x4;

__device__ inline float bf2f(unsigned short h) {
  union { unsigned u; float f; } v; v.u = (unsigned)h << 16; return v.f;
}
__device__ inline unsigned short f2bf(float f) {
  union { float f; unsigned u; } v; v.f = f;
  return (unsigned short)((v.u + 0x7FFFu + ((v.u >> 16) & 1u)) >> 16);
}

// ---------------------------------------------------------------------------
// x (fp32) -> x_bf16, 4 elems/thread
// ---------------------------------------------------------------------------
__global__ __launch_bounds__(256) void xconv_kernel(const float* __restrict__ x,
                                                    unsigned short* __restrict__ xb) {
  int i = blockIdx.x * 256 + threadIdx.x;
  if (i >= N_NODES * D / 4) return;
  float4 v = ((const float4*)x)[i];
  ushort4 o;
  o.x = f2bf(v.x); o.y = f2bf(v.y); o.z = f2bf(v.z); o.w = f2bf(v.w);
  ((ushort4*)xb)[i] = o;
}

// [W_self | W_agg] -> bf16 concat [128][256]; bsum = bself + bagg
__global__ __launch_bounds__(256) void wconv_kernel(
    const float* __restrict__ Wself, const float* __restrict__ Wagg,
    const float* __restrict__ bself, const float* __restrict__ bagg,
    unsigned short* __restrict__ wcat, float* __restrict__ bsum) {
  int t = blockIdx.x * 256 + threadIdx.x;
  if (t < 128 * 256) {
    int o = t >> 8, k = t & 255;
    float v = (k < 128) ? Wself[o * 128 + k] : Wagg[o * 128 + (k - 128)];
    wcat[o * 256 + k] = f2bf(v);
  }
  if (t < 128) bsum[t] = bself[t] + bagg[t];
}

// ---------------------------------------------------------------------------
// CSR build (unchanged from R2)
// ---------------------------------------------------------------------------
__global__ __launch_bounds__(256) void hist_kernel(const int* __restrict__ ei,
                                                   int* __restrict__ counts) {
  int e = blockIdx.x * 256 + threadIdx.x;
  if (e < N_EDGES) atomicAdd(&counts[ei[e]], 1);
}

__global__ __launch_bounds__(256) void scan_partials(const int* __restrict__ counts,
                                                     int* __restrict__ partials) {
  __shared__ int s[256];
  int i = blockIdx.x * 256 + threadIdx.x;
  s[threadIdx.x] = (i < N_NODES) ? counts[i] : 0;
  __syncthreads();
  for (int off = 128; off > 0; off >>= 1) {
    if (threadIdx.x < off) s[threadIdx.x] += s[threadIdx.x + off];
    __syncthreads();
  }
  if (threadIdx.x == 0) partials[blockIdx.x] = s[0];
}

__global__ __launch_bounds__(256) void scan_block(int* __restrict__ partials) {
  __shared__ int s[256];
  __shared__ int carry;
  if (threadIdx.x == 0) carry = 0;
  __syncthreads();
  for (int base = 0; base < NB; base += 256) {
    int i = base + threadIdx.x;
    int v = (i < NB) ? partials[i] : 0;
    s[threadIdx.x] = v;
    __syncthreads();
    for (int off = 1; off < 256; off <<= 1) {
      int t = (threadIdx.x >= off) ? s[threadIdx.x - off] : 0;
      __syncthreads();
      s[threadIdx.x] += t;
      __syncthreads();
    }
    int excl = s[threadIdx.x] - v + carry;
    if (i < NB) partials[i] = excl;
    __syncthreads();
    if (threadIdx.x == 0) carry += s[255];
    __syncthreads();
  }
}

__global__ __launch_bounds__(256) void scan_final(const int* __restrict__ counts,
                                                  const int* __restrict__ partials,
                                                  int* __restrict__ offsets,
                                                  int* __restrict__ cursor) {
  __shared__ int s[256];
  int i = blockIdx.x * 256 + threadIdx.x;
  int v = (i < N_NODES) ? counts[i] : 0;
  s[threadIdx.x] = v;
  __syncthreads();
  for (int off = 1; off < 256; off <<= 1) {
    int t = (threadIdx.x >= off) ? s[threadIdx.x - off] : 0;
    __syncthreads();
    s[threadIdx.x] += t;
    __syncthreads();
  }
  int excl = s[threadIdx.x] - v + partials[blockIdx.x];
  if (i < N_NODES) {
    offsets[i] = excl;
    cursor[i]  = excl;
  }
  if (i == N_NODES - 1) offsets[N_NODES] = N_EDGES;
}

__global__ __launch_bounds__(256) void scatter_csr(const int* __restrict__ ei,
                                                   int* __restrict__ cursor,
                                                   int* __restrict__ csr_col) {
  int e = blockIdx.x * 256 + threadIdx.x;
  if (e >= N_EDGES) return;
  int row = ei[e];
  int col = ei[N_EDGES + e];
  int pos = atomicAdd(&cursor[row], 1);
  csr_col[pos] = col;
}

// ---------------------------------------------------------------------------
// Pull-mode mean aggregation over bf16 x. One wave per node; 64 lanes x
// 1 uint (2 bf16) = 256 B per gathered row. Mean written as bf16 into the
// first 256 B of the node's d_out row (self-aliasing, overwritten by gemm).
// ---------------------------------------------------------------------------
__global__ __launch_bounds__(256) void aggregate_mean(
    const unsigned short* __restrict__ xb, const int* __restrict__ offsets,
    const int* __restrict__ csr_col, float* out) {
  int wave = (blockIdx.x * 256 + threadIdx.x) >> 6;
  int lane = threadIdx.x & 63;
  if (wave >= N_NODES) return;
  int beg = offsets[wave];
  int deg = offsets[wave + 1] - beg;
  float sx = 0.f, sy = 0.f;
  const unsigned* xw = (const unsigned*)xb;   // 64 uints per row
  for (int j0 = 0; j0 < deg; j0 += 64) {
    int cnt = deg - j0; if (cnt > 64) cnt = 64;
    int c = (j0 + lane < deg) ? csr_col[beg + j0 + lane] : 0;
    for (int e = 0; e < cnt; ++e) {
      int col = __shfl(c, e, 64);
      unsigned p = xw[col * 64 + lane];
      sx += bf2f((unsigned short)(p & 0xFFFFu));
      sy += bf2f((unsigned short)(p >> 16));
    }
  }
  float inv = 1.0f / ((float)deg + MEAN_EPS);
  unsigned lo = f2bf(sx * inv), hi = f2bf(sy * inv);
  ((unsigned*)(out + (size_t)wave * D))[lane] = lo | (hi << 16);
}

// ---------------------------------------------------------------------------
// MFMA GEMM: C[100000x128] = [x_bf16 | mean_bf16] (K=256) @ Wcat^T
// Block: 128 nodes x 128 outs, 512 threads (8 waves), full K in LDS.
// Wave w: M rows (w&3)*32..+32, N cols (w>>2)*64..+64 -> 2x4 acc tiles.
// Row pad +8 bf16 (stride 264) -> only 2-way LDS bank aliasing (free).
// Epilogue: bias+relu -> h in LDS (stride 132 f32, reuses As) -> per-row
// wave shfl LayerNorm -> float2 coalesced stores.
// ---------------------------------------------------------------------------
__global__ __launch_bounds__(512) void gemm_mfma_ln(
    const unsigned short* __restrict__ xb, const float* out_mean,
    const unsigned short* __restrict__ wcat, const float* __restrict__ bsum,
    const float* __restrict__ gamma, const float* __restrict__ beta,
    float* out) {
  __shared__ unsigned short As[128 * 264];
  __shared__ unsigned short Bs[128 * 264];
  __shared__ float bias_s[128];

  const int t = threadIdx.x;
  const int w = t >> 6, lane = t & 63;
  const int q = lane >> 4, s = lane & 15;
  const int base = blockIdx.x * 128;

  if (t < 128) bias_s[t] = bsum[t];

  // stage B: 128 rows x 32 x 16B chunks
#pragma unroll
  for (int r = 0; r < 8; ++r) {
    int f = r * 512 + t;
    int row = f >> 5, c = f & 31;
    uint4 v = *(const uint4*)(wcat + row * 256 + c * 8);
    *(uint4*)(Bs + row * 264 + c * 8) = v;
  }
  // stage A: chunks 0-15 from x_bf16, 16-31 from mean_bf16 (in d_out rows)
#pragma unroll
  for (int r = 0; r < 8; ++r) {
    int f = r * 512 + t;
    int row = f >> 5, c = f & 31;
    int node = base + row;
    uint4 v = make_uint4(0, 0, 0, 0);
    if (node < N_NODES) {
      const unsigned short* src = (c < 16)
          ? xb + (size_t)node * 128 + c * 8
          : (const unsigned short*)(out_mean + (size_t)node * 128) + (c - 16) * 8;
      v = *(const uint4*)src;
    }
    *(uint4*)(As + row * 264 + c * 8) = v;
  }
  __syncthreads();

  const int mrow = (w & 3) * 32;
  const int ncol = (w >> 2) * 64;

  f32x4 acc[2][4];
#pragma unroll
  for (int i = 0; i < 2; ++i)
#pragma unroll
    for (int j = 0; j < 4; ++j) acc[i][j] = (f32x4)(0.0f);

#pragma unroll
  for (int kk = 0; kk < 8; ++kk) {
    int ko = kk * 32 + q * 8;
    bf16x8 a0 = *(const bf16x8*)(As + (mrow + s) * 264 + ko);
    bf16x8 a1 = *(const bf16x8*)(As + (mrow + 16 + s) * 264 + ko);
    bf16x8 bv[4];
#pragma unroll
    for (int j = 0; j < 4; ++j)
      bv[j] = *(const bf16x8*)(Bs + (ncol + j * 16 + s) * 264 + ko);
#pragma unroll
    for (int j = 0; j < 4; ++j) {
      acc[0][j] = __builtin_amdgcn_mfma_f32_16x16x32_bf16(a0, bv[j], acc[0][j], 0, 0, 0);
      acc[1][j] = __builtin_amdgcn_mfma_f32_16x16x32_bf16(a1, bv[j], acc[1][j], 0, 0, 0);
    }
  }
  __syncthreads();   // done reading As; reuse as h buffer

  float* hS = (float*)As;  // [128][132]
#pragma unroll
  for (int i = 0; i < 2; ++i)
#pragma unroll
    for (int j = 0; j < 4; ++j)
#pragma unroll
      for (int r = 0; r < 4; ++r) {
        int row = mrow + i * 16 + q * 4 + r;
        int col = ncol + j * 16 + s;
        float h = acc[i][j][r] + bias_s[col];
        hS[row * 132 + col] = fmaxf(h, 0.0f);
      }
  __syncthreads();

  // LayerNorm: wave w handles rows w*16 .. w*16+15; lane covers cols 2l,2l+1
  float gx = gamma[2 * lane], gy = gamma[2 * lane + 1];
  float bx = beta[2 * lane],  by = beta[2 * lane + 1];
#pragma unroll 4
  for (int rr = 0; rr < 16; ++rr) {
    int row = w * 16 + rr;
    int node = base + row;
    float v0 = hS[row * 132 + 2 * lane];
    float v1 = hS[row * 132 + 2 * lane + 1];
    float s1 = v0 + v1, s2 = v0 * v0 + v1 * v1;
#pragma unroll
    for (int m = 1; m < 64; m <<= 1) {
      s1 += __shfl_xor(s1, m, 64);
      s2 += __shfl_xor(s2, m, 64);
    }
    float mu = s1 * (1.0f / 128.0f);
    float var = s2 * (1.0f / 128.0f) - mu * mu;
    float rstd = rsqrtf(var + LN_EPS);
    if (node < N_NODES) {
      float2 o;
      o.x = (v0 - mu) * rstd * gx + bx;
      o.y = (v1 - mu) * rstd * gy + by;
      *(float2*)(out + (size_t)node * 128 + 2 * lane) = o;
    }
  }
}

extern "C" void kernel_launch(void* const* d_in, const int* in_sizes, int n_in,
                              void* d_out, int out_size, void* d_ws, size_t ws_size,
                              hipStream_t stream) {
  const float* x     = (const float*)d_in[0];
  const int*   ei    = (const int*)d_in[1];
  const float* Wagg  = (const float*)d_in[2];
  const float* bagg  = (const float*)d_in[3];
  const float* Wself = (const float*)d_in[4];
  const float* bself = (const float*)d_in[5];
  const float* gamma = (const float*)d_in[6];
  const float* beta  = (const float*)d_in[7];
  float* out = (float*)d_out;

  // ws layout: x_bf16 | wcat_bf16 | bsum | counts | partials | offsets | cursor | csr_col
  unsigned short* xb   = (unsigned short*)d_ws;            // 12.8M bf16 (25.6 MB)
  unsigned short* wcat = xb + (size_t)N_NODES * D;         // 32768 bf16
  float* bsum     = (float*)(wcat + 128 * 256);            // 128 f32
  int* counts     = (int*)(bsum + 128);                    // N_NODES
  int* partials   = counts + N_NODES;                      // 512
  int* offsets    = partials + 512;                        // N_NODES + 1
  int* cursor     = offsets + N_NODES + 1;                 // N_NODES
  int* csr_col    = cursor + N_NODES;                      // N_EDGES

  hipMemsetAsync(counts, 0, N_NODES * sizeof(int), stream);

  xconv_kernel<<<(N_NODES * D / 4 + 255) / 256, 256, 0, stream>>>(x, xb);
  wconv_kernel<<<128, 256, 0, stream>>>(Wself, Wagg, bself, bagg, wcat, bsum);

  int eb = (N_EDGES + 255) / 256;
  hist_kernel<<<eb, 256, 0, stream>>>(ei, counts);
  scan_partials<<<NB, 256, 0, stream>>>(counts, partials);
  scan_block<<<1, 256, 0, stream>>>(partials);
  scan_final<<<NB, 256, 0, stream>>>(counts, partials, offsets, cursor);
  scatter_csr<<<eb, 256, 0, stream>>>(ei, cursor, csr_col);

  int ab = (N_NODES * 64 + 255) / 256;   // one wave per node
  aggregate_mean<<<ab, 256, 0, stream>>>(xb, offsets, csr_col, out);

  int gb = (N_NODES + 127) / 128;        // 782
  gemm_mfma_ln<<<gb, 512, 0, stream>>>(xb, out, wcat, bsum, gamma, beta, out);
}